// Round 6
// baseline (241.761 us; speedup 1.0000x reference)
//
#include <hip/hip_runtime.h>
#include <math.h>

#define NB 256
#define NN 64
#define ND 64
#define TOT (NB*NN*ND)           // 1048576
#define EPS_SINK 1e-8f
#define THR (1.0f/64.0f)
#define INV_BSCALE 0.5412658773652741f   // 1/sqrt(2+sqrt(2))
#define UNTANH_A 0.6f

typedef float nativef4 __attribute__((ext_vector_type(4)));

static __device__ __forceinline__ float buntanh(float x) {
    return (tanhf(x) + UNTANH_A * x) * INV_BSCALE;
}

// ---- cross-lane helpers: proven __shfl_xor only ---------------------------
// all-reduce over lane bits 0-3 (16-lane group)
static __device__ __forceinline__ float row16_add(float x) {
    x += __shfl_xor(x, 1, 64);
    x += __shfl_xor(x, 2, 64);
    x += __shfl_xor(x, 4, 64);
    x += __shfl_xor(x, 8, 64);
    return x;
}
static __device__ __forceinline__ float row16_max(float x) {
    x = fmaxf(x, __shfl_xor(x, 1, 64));
    x = fmaxf(x, __shfl_xor(x, 2, 64));
    x = fmaxf(x, __shfl_xor(x, 4, 64));
    x = fmaxf(x, __shfl_xor(x, 8, 64));
    return x;
}
static __device__ __forceinline__ float hi32_add(float x) {   // bits 4,5
    x += __shfl_xor(x, 16, 64);
    x += __shfl_xor(x, 32, 64);
    return x;
}
static __device__ __forceinline__ float hi32_max(float x) {
    x = fmaxf(x, __shfl_xor(x, 16, 64));
    x = fmaxf(x, __shfl_xor(x, 32, 64));
    return x;
}

// ---------------------------------------------------------------------------
// K1 v4 (shfl reduce): pred/keys/queries = buntanh(state[b,n,:] @ w[b,n,:,:])
// Coalesced remap: lane l reads W floats [jj*256 + l*4, +4) = row (4jj+l>>4),
// cols 4*(l&15)..+3 -> every wave float4-load is 1 KB CONTIGUOUS.
// s fragment: s[jj] = state[bn*64 + 4*jj + jg] (stride-4 scalar, cached).
// Reduce over jg (rows mod 4) = xor16 + xor32. 8 tasks/wave, NT loads.
// ---------------------------------------------------------------------------
__global__ __launch_bounds__(256) void gemv_buntanh_kernel(
    const float* __restrict__ state,
    const float* __restrict__ w1, const float* __restrict__ w2,
    const float* __restrict__ w3,
    float* __restrict__ pred, float* __restrict__ keys,
    float* __restrict__ quer)
{
    const int wave = threadIdx.x >> 6;
    const int lane = threadIdx.x & 63;
    const int wgid = blockIdx.x * 4 + wave;       // 0..6143
    const int jg = lane >> 4;
    const int k4 = lane & 15;
    const int task0 = wgid * 8;                   // 8 consecutive tasks
    const int widx = task0 >> 14;                 // uniform over the group
    const int bn0 = task0 & 16383;

    const float* __restrict__ w = (widx == 0) ? w1 : (widx == 1) ? w2 : w3;
    float* __restrict__ outp = (widx == 0) ? pred : (widx == 1) ? keys : quer;

#pragma unroll
    for (int tt = 0; tt < 8; ++tt) {
        const int bn = bn0 + tt;

        const float* sp = state + bn * 64 + jg;
        float s[16];
#pragma unroll
        for (int jj = 0; jj < 16; ++jj) s[jj] = sp[4 * jj];

        const nativef4* wp = (const nativef4*)(w + (size_t)bn * 4096) + lane;
        float a0 = 0.f, a1 = 0.f, a2 = 0.f, a3 = 0.f;
#pragma unroll
        for (int jj = 0; jj < 16; ++jj) {
            nativef4 wv4 = __builtin_nontemporal_load(wp + jj * 64);  // 1KB/wave
            a0 = fmaf(s[jj], wv4.x, a0);
            a1 = fmaf(s[jj], wv4.y, a1);
            a2 = fmaf(s[jj], wv4.z, a2);
            a3 = fmaf(s[jj], wv4.w, a3);
        }
        a0 = hi32_add(a0);
        a1 = hi32_add(a1);
        a2 = hi32_add(a2);
        a3 = hi32_add(a3);
        if (jg == 0) {
            float4 o4;
            o4.x = buntanh(a0);
            o4.y = buntanh(a1);
            o4.z = buntanh(a2);
            o4.w = buntanh(a3);
            *(float4*)(outp + bn * 64 + k4 * 4) = o4;
        }
    }
}

// ---------------------------------------------------------------------------
// K2 v3 (shfl reduce): per (b,h): scores -> rmsnorm -> register sinkhorn(10)
//        -> threshold -> A@V -> fused loss partials. P entirely in registers.
// Thread (wv=t>>6, l=t&63): gr=(wv<<2)|(l>>4) rows 4gr..+3,
//                           gc=l&15          cols 4gc..+3.
// Row reduce (over gc): shfl_xor 1,2,4,8.
// Col reduce (over gr): shfl_xor 16,32 + cross-wave LDS, 1 barrier/iter.
// ---------------------------------------------------------------------------
__global__ __launch_bounds__(256) void attn_sinkhorn_loss_kernel(
    const float* __restrict__ pred, const float* __restrict__ keys,
    const float* __restrict__ quer, const float* __restrict__ state,
    const float* __restrict__ env, float* __restrict__ part)
{
    __shared__ float4 Qs[64];
    __shared__ float4 Ks[64];
    __shared__ float4 Vs[64];
    __shared__ float4 Ss[64];
    __shared__ float4 cp4[2][4][16];
    __shared__ float redS[4], redM[4];
    __shared__ float redL[4][3];

    const int blk = blockIdx.x;     // b*16 + h
    const int b = blk >> 4;
    const int h = blk & 15;
    const int t = threadIdx.x;
    const int wv = t >> 6;
    const int l = t & 63;
    const int gr = (wv << 2) | (l >> 4);   // row group 0..15
    const int gc = l & 15;                 // col group 0..15

    {
        const size_t off = ((size_t)(b * 64 + l)) * 64 + h * 4;
        if (wv == 0)      Qs[l] = *(const float4*)(quer + off);
        else if (wv == 1) Ks[l] = *(const float4*)(keys + off);
        else if (wv == 2) Vs[l] = *(const float4*)(pred + off);
        else              Ss[l] = *(const float4*)(state + off);
    }
    __syncthreads();

    // ---- scores into registers, with sum-of-squares and max ----
    float p[4][4];
    float ss = 0.f, mx = -1e30f;
    {
        float4 kk[4];
#pragma unroll
        for (int j = 0; j < 4; ++j) kk[j] = Ks[4 * gc + j];
#pragma unroll
        for (int i = 0; i < 4; ++i) {
            const float4 q = Qs[4 * gr + i];
#pragma unroll
            for (int j = 0; j < 4; ++j) {
                float e = (q.x * kk[j].x + q.y * kk[j].y +
                           q.z * kk[j].z + q.w * kk[j].w) * 0.5f;
                p[i][j] = e;
                ss += e * e;
                mx = fmaxf(mx, e);
            }
        }
    }
    ss = hi32_add(row16_add(ss));
    mx = hi32_max(row16_max(mx));
    if (l == 0) { redS[wv] = ss; redM[wv] = mx; }
    __syncthreads();
    ss = redS[0] + redS[1] + redS[2] + redS[3];
    mx = fmaxf(fmaxf(redM[0], redM[1]), fmaxf(redM[2], redM[3]));
    const float scale = rsqrtf(ss * (1.0f / 4096.0f) + 1e-6f);  // SHARPNESS=1

#pragma unroll
    for (int i = 0; i < 4; ++i)
#pragma unroll
        for (int j = 0; j < 4; ++j)
            p[i][j] = expf(scale * (p[i][j] - mx));

    // ---- sinkhorn: 10 x (row-normalize, col-normalize) ----
    int buf = 0;
    for (int it = 0; it < 10; ++it) {
        // row phase: reduce over the 16 gc lanes
#pragma unroll
        for (int i = 0; i < 4; ++i) {
            float r = p[i][0] + p[i][1] + p[i][2] + p[i][3];
            r = row16_add(r);
            const float inv = 1.0f / (r + EPS_SINK);
            p[i][0] *= inv; p[i][1] *= inv; p[i][2] *= inv; p[i][3] *= inv;
        }
        // col phase: xor16+xor32 within wave, then cross-wave LDS
        float c0 = p[0][0] + p[1][0] + p[2][0] + p[3][0];
        float c1 = p[0][1] + p[1][1] + p[2][1] + p[3][1];
        float c2 = p[0][2] + p[1][2] + p[2][2] + p[3][2];
        float c3 = p[0][3] + p[1][3] + p[2][3] + p[3][3];
        c0 = hi32_add(c0);
        c1 = hi32_add(c1);
        c2 = hi32_add(c2);
        c3 = hi32_add(c3);
        if (l < 16) cp4[buf][wv][l] = make_float4(c0, c1, c2, c3);
        __syncthreads();
        {
            const float4 a0 = cp4[buf][0][gc];
            const float4 a1 = cp4[buf][1][gc];
            const float4 a2 = cp4[buf][2][gc];
            const float4 a3 = cp4[buf][3][gc];
            const float i0 = 1.0f / (a0.x + a1.x + a2.x + a3.x + EPS_SINK);
            const float i1 = 1.0f / (a0.y + a1.y + a2.y + a3.y + EPS_SINK);
            const float i2 = 1.0f / (a0.z + a1.z + a2.z + a3.z + EPS_SINK);
            const float i3 = 1.0f / (a0.w + a1.w + a2.w + a3.w + EPS_SINK);
#pragma unroll
            for (int i = 0; i < 4; ++i) {
                p[i][0] *= i0; p[i][1] *= i1; p[i][2] *= i2; p[i][3] *= i3;
            }
        }
        buf ^= 1;
    }

    // ---- threshold in regs, A@V partials, all-reduce over gc ----
#pragma unroll
    for (int i = 0; i < 4; ++i)
#pragma unroll
        for (int j = 0; j < 4; ++j)
            p[i][j] = (p[i][j] > THR) ? p[i][j] : 0.f;

    float rp[4][4];   // [i][d] routed_V for row 4gr+i, dim d
    {
        float4 vv[4];
#pragma unroll
        for (int j = 0; j < 4; ++j) vv[j] = Vs[4 * gc + j];
#pragma unroll
        for (int i = 0; i < 4; ++i) {
            float a0 = 0.f, a1 = 0.f, a2 = 0.f, a3 = 0.f;
#pragma unroll
            for (int j = 0; j < 4; ++j) {
                a0 = fmaf(p[i][j], vv[j].x, a0);
                a1 = fmaf(p[i][j], vv[j].y, a1);
                a2 = fmaf(p[i][j], vv[j].z, a2);
                a3 = fmaf(p[i][j], vv[j].w, a3);
            }
            rp[i][0] = row16_add(a0);
            rp[i][1] = row16_add(a1);
            rp[i][2] = row16_add(a2);
            rp[i][3] = row16_add(a3);
        }
    }

    // ---- fused loss: lane gc<4 handles dim d=gc for its 4 rows ----
    float l1 = 0.f, l2 = 0.f, l3 = 0.f;
    if (gc < 4) {
        const int d = gc;
#pragma unroll
        for (int i = 0; i < 4; ++i) {
            const int n = 4 * gr + i;
            const float rv = (d == 0) ? rp[i][0] : (d == 1) ? rp[i][1]
                           : (d == 2) ? rp[i][2] : rp[i][3];
            float tv;
            if (n < 2) {
                const int idx = n * 64 + h * 4 + d;
                tv = (idx < 100) ? env[b * 100 + idx] : 0.f;
            } else {
                tv = rv;
            }
            const float pv = ((const float*)&Vs[n])[d];
            const float kk = ((const float*)&Ks[n])[d];
            const float qv = ((const float*)&Qs[n])[d];
            const float sv = ((const float*)&Ss[n])[d];
            const float d1 = pv - tv;
            const float d2 = kk - sv;
            const float d3 = qv - tv;
            l1 = fmaf(d1, d1, l1);
            l2 = fmaf(d2, d2, l2);
            l3 = fmaf(d3, d3, l3);
        }
    }
    l1 = hi32_add(row16_add(l1));
    l2 = hi32_add(row16_add(l2));
    l3 = hi32_add(row16_add(l3));
    if (l == 0) { redL[wv][0] = l1; redL[wv][1] = l2; redL[wv][2] = l3; }
    __syncthreads();
    if (t == 0) {
        part[blk]        = redL[0][0] + redL[1][0] + redL[2][0] + redL[3][0];
        part[4096 + blk] = redL[0][1] + redL[1][1] + redL[2][1] + redL[3][1];
        part[8192 + blk] = redL[0][2] + redL[1][2] + redL[2][2] + redL[3][2];
    }
}

// ---------------------------------------------------------------------------
// K3: final reduce -> scalar loss
// ---------------------------------------------------------------------------
__global__ __launch_bounds__(256) void loss_final_kernel(
    const float* __restrict__ part, float* __restrict__ out)
{
    float a = 0.f;
    for (int i = threadIdx.x; i < 12288; i += 256) a += part[i];
#pragma unroll
    for (int o = 32; o >= 1; o >>= 1) a += __shfl_xor(a, o, 64);
    __shared__ float red[4];
    const int wv = threadIdx.x >> 6, ln = threadIdx.x & 63;
    if (ln == 0) red[wv] = a;
    __syncthreads();
    if (threadIdx.x == 0) {
        out[0] = (red[0] + red[1] + red[2] + red[3]) * (1.0f / (float)TOT);
    }
}

extern "C" void kernel_launch(void* const* d_in, const int* in_sizes, int n_in,
                              void* d_out, int out_size, void* d_ws, size_t ws_size,
                              hipStream_t stream)
{
    const float* env   = (const float*)d_in[0];
    const float* state = (const float*)d_in[1];
    const float* w1    = (const float*)d_in[2];
    const float* w2    = (const float*)d_in[3];
    const float* w3    = (const float*)d_in[4];
    float* out = (float*)d_out;

    float* wsf  = (float*)d_ws;
    float* pred = wsf;
    float* keys = wsf + 1 * TOT;
    float* quer = wsf + 2 * TOT;
    float* part = wsf + 3 * TOT;   // 3*4096 floats

    hipLaunchKernelGGL(gemv_buntanh_kernel, dim3(1536), dim3(256), 0, stream,
                       state, w1, w2, w3, pred, keys, quer);
    hipLaunchKernelGGL(attn_sinkhorn_loss_kernel, dim3(4096), dim3(256), 0, stream,
                       pred, keys, quer, state, env, part);
    hipLaunchKernelGGL(loss_final_kernel, dim3(1), dim3(256), 0, stream,
                       part, out);
}

// Round 7
// 200.188 us; speedup vs baseline: 1.2077x; 1.2077x over previous
//
#include <hip/hip_runtime.h>
#include <math.h>

#define NB 256
#define NN 64
#define ND 64
#define TOT (NB*NN*ND)           // 1048576
#define EPS_SINK 1e-8f
#define THR (1.0f/64.0f)
#define INV_BSCALE 0.5412658773652741f   // 1/sqrt(2+sqrt(2))
#define UNTANH_A 0.6f

typedef float nativef4 __attribute__((ext_vector_type(4)));

static __device__ __forceinline__ float buntanh(float x) {
    return (tanhf(x) + UNTANH_A * x) * INV_BSCALE;
}

#if __has_builtin(__builtin_amdgcn_rcpf)
static __device__ __forceinline__ float fastrcp(float x) {
    return __builtin_amdgcn_rcpf(x);
}
#else
static __device__ __forceinline__ float fastrcp(float x) { return 1.0f / x; }
#endif

// ---------------------------------------------------------------------------
// K1: pred/keys/queries = buntanh(state[b,n,:] @ w[b,n,:,:])
// 4 tasks/wave (measured-best grid), NT weight loads, contiguous 1KB wave
// loads: lane l reads W row (4jj + l>>4), cols 4*(l&15)..+3.
// Reduce over jg = xor16 + xor32.
// ---------------------------------------------------------------------------
__global__ __launch_bounds__(256) void gemv_buntanh_kernel(
    const float* __restrict__ state,
    const float* __restrict__ w1, const float* __restrict__ w2,
    const float* __restrict__ w3,
    float* __restrict__ pred, float* __restrict__ keys,
    float* __restrict__ quer)
{
    const int wave = threadIdx.x >> 6;
    const int lane = threadIdx.x & 63;
    const int wgid = blockIdx.x * 4 + wave;       // 0..12287
    const int jg = lane >> 4;
    const int k4 = lane & 15;
    const int task0 = wgid * 4;                   // 4 consecutive tasks
    const int widx = task0 >> 14;                 // uniform over the group
    const int bn0 = task0 & 16383;

    const float* __restrict__ w = (widx == 0) ? w1 : (widx == 1) ? w2 : w3;
    float* __restrict__ outp = (widx == 0) ? pred : (widx == 1) ? keys : quer;

#pragma unroll
    for (int tt = 0; tt < 4; ++tt) {
        const int bn = bn0 + tt;

        const float* sp = state + bn * 64 + jg;
        float s[16];
#pragma unroll
        for (int jj = 0; jj < 16; ++jj) s[jj] = sp[4 * jj];

        const nativef4* wp = (const nativef4*)(w + (size_t)bn * 4096) + lane;
        float a0 = 0.f, a1 = 0.f, a2 = 0.f, a3 = 0.f;
#pragma unroll
        for (int jj = 0; jj < 16; ++jj) {
            nativef4 wv4 = __builtin_nontemporal_load(wp + jj * 64);  // 1KB/wave
            a0 = fmaf(s[jj], wv4.x, a0);
            a1 = fmaf(s[jj], wv4.y, a1);
            a2 = fmaf(s[jj], wv4.z, a2);
            a3 = fmaf(s[jj], wv4.w, a3);
        }
        a0 += __shfl_xor(a0, 16, 64); a0 += __shfl_xor(a0, 32, 64);
        a1 += __shfl_xor(a1, 16, 64); a1 += __shfl_xor(a1, 32, 64);
        a2 += __shfl_xor(a2, 16, 64); a2 += __shfl_xor(a2, 32, 64);
        a3 += __shfl_xor(a3, 16, 64); a3 += __shfl_xor(a3, 32, 64);
        if (jg == 0) {
            float4 o4;
            o4.x = buntanh(a0);
            o4.y = buntanh(a1);
            o4.z = buntanh(a2);
            o4.w = buntanh(a3);
            *(float4*)(outp + bn * 64 + k4 * 4) = o4;
        }
    }
}

// ---------------------------------------------------------------------------
// K2 v4: ONE WAVE per (b,h). Zero barriers, zero LDS.
// Lane l: rg=l>>3 owns rows 8rg..+7; cg=l&7 owns cols 8cg..+7 (8x8 subtile
// of P in 64 VGPRs). Row sums: shfl_xor 1,2,4 (lanes sharing rg).
// Col sums: shfl_xor 8,16,32 (lanes sharing cg). rcp for all divides,
// __expf for exp. Q/K/V/loss rows re-read from L2-hot global.
// 4 independent waves per 256-thread block.
// ---------------------------------------------------------------------------
__global__ __launch_bounds__(256) void attn_sinkhorn_loss_kernel(
    const float* __restrict__ pred, const float* __restrict__ keys,
    const float* __restrict__ quer, const float* __restrict__ state,
    const float* __restrict__ env, float* __restrict__ part)
{
    const int wave = threadIdx.x >> 6;
    const int l = threadIdx.x & 63;
    const int task = blockIdx.x * 4 + wave;   // 0..4095 = b*16 + h
    const int b = task >> 4;
    const int h = task & 15;
    const int rg = l >> 3;                    // row group: rows 8rg..+7
    const int cg = l & 7;                     // col group: cols 8cg..+7
    const size_t base = (size_t)(b * 64) * 64 + h * 4;

    // ---- scores p[i][j] = 0.5 * Q[8rg+i] . K[8cg+j], with ss and max ----
    float p[8][8];
    float ss = 0.f, mx = -1e30f;
    {
        float4 qf[8], kf[8];
#pragma unroll
        for (int i = 0; i < 8; ++i)
            qf[i] = *(const float4*)(quer + base + (size_t)(8 * rg + i) * 64);
#pragma unroll
        for (int j = 0; j < 8; ++j)
            kf[j] = *(const float4*)(keys + base + (size_t)(8 * cg + j) * 64);
#pragma unroll
        for (int i = 0; i < 8; ++i) {
#pragma unroll
            for (int j = 0; j < 8; ++j) {
                float e = (qf[i].x * kf[j].x + qf[i].y * kf[j].y +
                           qf[i].z * kf[j].z + qf[i].w * kf[j].w) * 0.5f;
                p[i][j] = e;
                ss += e * e;
                mx = fmaxf(mx, e);
            }
        }
    }
#pragma unroll
    for (int o = 1; o <= 32; o <<= 1) {
        ss += __shfl_xor(ss, o, 64);
        mx = fmaxf(mx, __shfl_xor(mx, o, 64));
    }
    const float scale = rsqrtf(ss * (1.0f / 4096.0f) + 1e-6f);  // SHARPNESS=1

#pragma unroll
    for (int i = 0; i < 8; ++i)
#pragma unroll
        for (int j = 0; j < 8; ++j)
            p[i][j] = __expf(scale * (p[i][j] - mx));

    // ---- sinkhorn: 10 x (row-normalize, col-normalize), wave-local ----
    for (int it = 0; it < 10; ++it) {
#pragma unroll
        for (int i = 0; i < 8; ++i) {
            float r = ((p[i][0] + p[i][1]) + (p[i][2] + p[i][3])) +
                      ((p[i][4] + p[i][5]) + (p[i][6] + p[i][7]));
            r += __shfl_xor(r, 1, 64);
            r += __shfl_xor(r, 2, 64);
            r += __shfl_xor(r, 4, 64);
            const float inv = fastrcp(r + EPS_SINK);
#pragma unroll
            for (int j = 0; j < 8; ++j) p[i][j] *= inv;
        }
#pragma unroll
        for (int j = 0; j < 8; ++j) {
            float c = ((p[0][j] + p[1][j]) + (p[2][j] + p[3][j])) +
                      ((p[4][j] + p[5][j]) + (p[6][j] + p[7][j]));
            c += __shfl_xor(c, 8, 64);
            c += __shfl_xor(c, 16, 64);
            c += __shfl_xor(c, 32, 64);
            const float inv = fastrcp(c + EPS_SINK);
#pragma unroll
            for (int i = 0; i < 8; ++i) p[i][j] *= inv;
        }
    }

    // ---- threshold ----
#pragma unroll
    for (int i = 0; i < 8; ++i)
#pragma unroll
        for (int j = 0; j < 8; ++j)
            p[i][j] = (p[i][j] > THR) ? p[i][j] : 0.f;

    // ---- A@V: o[i][d] partial over own cols, butterfly over cg ----
    float o8[8][4];
    {
        float4 vf[8];
#pragma unroll
        for (int j = 0; j < 8; ++j)
            vf[j] = *(const float4*)(pred + base + (size_t)(8 * cg + j) * 64);
#pragma unroll
        for (int i = 0; i < 8; ++i) {
            float d0 = 0.f, d1 = 0.f, d2 = 0.f, d3 = 0.f;
#pragma unroll
            for (int j = 0; j < 8; ++j) {
                d0 = fmaf(p[i][j], vf[j].x, d0);
                d1 = fmaf(p[i][j], vf[j].y, d1);
                d2 = fmaf(p[i][j], vf[j].z, d2);
                d3 = fmaf(p[i][j], vf[j].w, d3);
            }
            o8[i][0] = d0; o8[i][1] = d1; o8[i][2] = d2; o8[i][3] = d3;
        }
    }
#pragma unroll
    for (int i = 0; i < 8; ++i)
#pragma unroll
        for (int d = 0; d < 4; ++d) {
            float v = o8[i][d];
            v += __shfl_xor(v, 1, 64);
            v += __shfl_xor(v, 2, 64);
            v += __shfl_xor(v, 4, 64);
            o8[i][d] = v;
        }

    // ---- fused loss: lane handles row n = 8rg + cg (all 64 rows covered) ----
    float l1, l2, l3;
    {
        const int n = 8 * rg + cg;
        const float4 pv = *(const float4*)(pred + base + (size_t)n * 64);
        const float4 kv = *(const float4*)(keys + base + (size_t)n * 64);
        const float4 qv = *(const float4*)(quer + base + (size_t)n * 64);
        const float4 sv = *(const float4*)(state + base + (size_t)n * 64);
        float pa[4] = {pv.x, pv.y, pv.z, pv.w};
        float ka[4] = {kv.x, kv.y, kv.z, kv.w};
        float qa[4] = {qv.x, qv.y, qv.z, qv.w};
        float sa[4] = {sv.x, sv.y, sv.z, sv.w};
        l1 = 0.f; l2 = 0.f; l3 = 0.f;
#pragma unroll
        for (int d = 0; d < 4; ++d) {
            float tv;
            if (n < 2) {
                const int idx = n * 64 + h * 4 + d;
                tv = (idx < 100) ? env[b * 100 + idx] : 0.f;
            } else {
                tv = o8[cg][d];   // row n = 8rg+cg -> own i == cg
            }
            const float d1 = pa[d] - tv;
            const float d2 = ka[d] - sa[d];
            const float d3 = qa[d] - tv;
            l1 = fmaf(d1, d1, l1);
            l2 = fmaf(d2, d2, l2);
            l3 = fmaf(d3, d3, l3);
        }
    }
#pragma unroll
    for (int o = 1; o <= 32; o <<= 1) {
        l1 += __shfl_xor(l1, o, 64);
        l2 += __shfl_xor(l2, o, 64);
        l3 += __shfl_xor(l3, o, 64);
    }
    if (l == 0) {
        part[task]        = l1;
        part[4096 + task] = l2;
        part[8192 + task] = l3;
    }
}

// ---------------------------------------------------------------------------
// K3: final reduce -> scalar loss
// ---------------------------------------------------------------------------
__global__ __launch_bounds__(256) void loss_final_kernel(
    const float* __restrict__ part, float* __restrict__ out)
{
    float a = 0.f;
    for (int i = threadIdx.x; i < 12288; i += 256) a += part[i];
#pragma unroll
    for (int o = 32; o >= 1; o >>= 1) a += __shfl_xor(a, o, 64);
    __shared__ float red[4];
    const int wv = threadIdx.x >> 6, ln = threadIdx.x & 63;
    if (ln == 0) red[wv] = a;
    __syncthreads();
    if (threadIdx.x == 0) {
        out[0] = (red[0] + red[1] + red[2] + red[3]) * (1.0f / (float)TOT);
    }
}

extern "C" void kernel_launch(void* const* d_in, const int* in_sizes, int n_in,
                              void* d_out, int out_size, void* d_ws, size_t ws_size,
                              hipStream_t stream)
{
    const float* env   = (const float*)d_in[0];
    const float* state = (const float*)d_in[1];
    const float* w1    = (const float*)d_in[2];
    const float* w2    = (const float*)d_in[3];
    const float* w3    = (const float*)d_in[4];
    float* out = (float*)d_out;

    float* wsf  = (float*)d_ws;
    float* pred = wsf;
    float* keys = wsf + 1 * TOT;
    float* quer = wsf + 2 * TOT;
    float* part = wsf + 3 * TOT;   // 3*4096 floats

    hipLaunchKernelGGL(gemv_buntanh_kernel, dim3(3072), dim3(256), 0, stream,
                       state, w1, w2, w3, pred, keys, quer);
    hipLaunchKernelGGL(attn_sinkhorn_loss_kernel, dim3(1024), dim3(256), 0, stream,
                       pred, keys, quer, state, env, part);
    hipLaunchKernelGGL(loss_final_kernel, dim3(1), dim3(256), 0, stream,
                       part, out);
}

// Round 8
// 180.370 us; speedup vs baseline: 1.3404x; 1.1099x over previous
//
#include <hip/hip_runtime.h>
#include <math.h>

#define TOT (256*64*64)          // 1048576
#define EPS_SINK 1e-8f
#define THR (1.0f/64.0f)
#define INV_BSCALE 0.5412658773652741f   // 1/sqrt(2+sqrt(2))
#define UNTANH_A 0.6f

typedef float nativef4 __attribute__((ext_vector_type(4)));

static __device__ __forceinline__ float buntanh(float x) {
    return (tanhf(x) + UNTANH_A * x) * INV_BSCALE;
}

#if __has_builtin(__builtin_amdgcn_rcpf)
static __device__ __forceinline__ float fastrcp(float x) {
    return __builtin_amdgcn_rcpf(x);
}
#else
static __device__ __forceinline__ float fastrcp(float x) { return 1.0f / x; }
#endif

// ---------------------------------------------------------------------------
// Fused kernel: one block per (b, col-half). 512 threads = 8 waves.
// Phase 1: stage state[b] (16 KB) into LDS.
// Phase 2: 192 half-gemvs (w in {w1,w2,w3} x n in 0..63), each computing
//   out[b,n, half*32 .. +31] = buntanh(state[b,n,:] @ w[b,n,:,half-cols]).
//   Lane (r8=l>>3, c8=l&7): rows j0+r8, cols 4c8..+3; 8x NT dwordx4 loads
//   (8 aligned 128B segments/instr); reduce over r8 = xor 8,16,32.
//   Results -> LDS [64][33] (padded, bank-clean), never to global.
// Phase 3: 8 attn waves, one head each (head h = half*8 + wave uses cols
//   4*wave..+3 of the LDS arrays). Register-resident sinkhorn (r7 proven),
//   zero barriers; dynamic o8 index replaced by static cndmask select.
//   Fused loss partials -> part[3*512].
// ---------------------------------------------------------------------------
__global__ __launch_bounds__(512, 4) void fused_brain_kernel(
    const float* __restrict__ env, const float* __restrict__ state,
    const float* __restrict__ w1, const float* __restrict__ w2,
    const float* __restrict__ w3, float* __restrict__ part)
{
    __shared__ float Ss[64][65];     // full state rows (16.25 KB)
    __shared__ float Vh[64][33];     // pred  (half cols)
    __shared__ float Kh[64][33];     // keys
    __shared__ float Qh[64][33];     // queries
    __shared__ float redL[8][3];

    const int b    = blockIdx.x >> 1;
    const int half = blockIdx.x & 1;
    const int wave = threadIdx.x >> 6;
    const int l    = threadIdx.x & 63;
    const int r8   = l >> 3;         // 0..7
    const int c8   = l & 7;          // 0..7

    // ---- phase 1: stage state[b] ----
    {
        const float* sb = state + (size_t)b * 4096 + threadIdx.x * 8;
        const float4 v0 = *(const float4*)(sb);
        const float4 v1 = *(const float4*)(sb + 4);
        const int row = threadIdx.x >> 3;
        const int col = (threadIdx.x & 7) * 8;
        Ss[row][col + 0] = v0.x; Ss[row][col + 1] = v0.y;
        Ss[row][col + 2] = v0.z; Ss[row][col + 3] = v0.w;
        Ss[row][col + 4] = v1.x; Ss[row][col + 5] = v1.y;
        Ss[row][col + 6] = v1.z; Ss[row][col + 7] = v1.w;
    }
    __syncthreads();

    // ---- phase 2: gemv (24 half-tasks per wave) ----
    for (int tt = 0; tt < 24; ++tt) {
        const int task = wave * 24 + tt;       // 0..191
        const int widx = task >> 6;            // 0,1,2
        const int n    = task & 63;
        const float* __restrict__ w =
            (widx == 0) ? w1 : (widx == 1) ? w2 : w3;
        const float* wp = w + ((size_t)(b * 64 + n)) * 4096 + half * 32 + 4 * c8;

        float a0 = 0.f, a1 = 0.f, a2 = 0.f, a3 = 0.f;
#pragma unroll
        for (int j0 = 0; j0 < 64; j0 += 8) {
            const nativef4 wv =
                __builtin_nontemporal_load((const nativef4*)(wp + (j0 + r8) * 64));
            const float sj = Ss[n][j0 + r8];
            a0 = fmaf(sj, wv.x, a0);
            a1 = fmaf(sj, wv.y, a1);
            a2 = fmaf(sj, wv.z, a2);
            a3 = fmaf(sj, wv.w, a3);
        }
        a0 += __shfl_xor(a0, 8, 64); a0 += __shfl_xor(a0, 16, 64); a0 += __shfl_xor(a0, 32, 64);
        a1 += __shfl_xor(a1, 8, 64); a1 += __shfl_xor(a1, 16, 64); a1 += __shfl_xor(a1, 32, 64);
        a2 += __shfl_xor(a2, 8, 64); a2 += __shfl_xor(a2, 16, 64); a2 += __shfl_xor(a2, 32, 64);
        a3 += __shfl_xor(a3, 8, 64); a3 += __shfl_xor(a3, 16, 64); a3 += __shfl_xor(a3, 32, 64);
        a0 = buntanh(a0); a1 = buntanh(a1); a2 = buntanh(a2); a3 = buntanh(a3);
        if (r8 == 0) {
            float* dst = (widx == 0) ? &Vh[n][4 * c8]
                       : (widx == 1) ? &Kh[n][4 * c8] : &Qh[n][4 * c8];
            dst[0] = a0; dst[1] = a1; dst[2] = a2; dst[3] = a3;
        }
    }
    __syncthreads();

    // ---- phase 3: attention + sinkhorn + loss. wave = local head hl ----
    const int cb = 4 * wave;        // local col base of this head
    const int rg = r8, cg = c8;

    float p[8][8];
    float ss = 0.f, mx = -1e30f;
    {
        float kq[8][4];
#pragma unroll
        for (int j = 0; j < 8; ++j)
#pragma unroll
            for (int d = 0; d < 4; ++d)
                kq[j][d] = Kh[8 * cg + j][cb + d];
#pragma unroll
        for (int i = 0; i < 8; ++i) {
            const float q0 = Qh[8 * rg + i][cb + 0];
            const float q1 = Qh[8 * rg + i][cb + 1];
            const float q2 = Qh[8 * rg + i][cb + 2];
            const float q3 = Qh[8 * rg + i][cb + 3];
#pragma unroll
            for (int j = 0; j < 8; ++j) {
                const float e = (q0 * kq[j][0] + q1 * kq[j][1] +
                                 q2 * kq[j][2] + q3 * kq[j][3]) * 0.5f;
                p[i][j] = e;
                ss += e * e;
                mx = fmaxf(mx, e);
            }
        }
    }
#pragma unroll
    for (int o = 1; o <= 32; o <<= 1) {
        ss += __shfl_xor(ss, o, 64);
        mx = fmaxf(mx, __shfl_xor(mx, o, 64));
    }
    const float scale = rsqrtf(ss * (1.0f / 4096.0f) + 1e-6f);  // SHARPNESS=1

#pragma unroll
    for (int i = 0; i < 8; ++i)
#pragma unroll
        for (int j = 0; j < 8; ++j)
            p[i][j] = __expf(scale * (p[i][j] - mx));

    for (int it = 0; it < 10; ++it) {
#pragma unroll
        for (int i = 0; i < 8; ++i) {
            float r = ((p[i][0] + p[i][1]) + (p[i][2] + p[i][3])) +
                      ((p[i][4] + p[i][5]) + (p[i][6] + p[i][7]));
            r += __shfl_xor(r, 1, 64);
            r += __shfl_xor(r, 2, 64);
            r += __shfl_xor(r, 4, 64);
            const float inv = fastrcp(r + EPS_SINK);
#pragma unroll
            for (int j = 0; j < 8; ++j) p[i][j] *= inv;
        }
#pragma unroll
        for (int j = 0; j < 8; ++j) {
            float c = ((p[0][j] + p[1][j]) + (p[2][j] + p[3][j])) +
                      ((p[4][j] + p[5][j]) + (p[6][j] + p[7][j]));
            c += __shfl_xor(c, 8, 64);
            c += __shfl_xor(c, 16, 64);
            c += __shfl_xor(c, 32, 64);
            const float inv = fastrcp(c + EPS_SINK);
#pragma unroll
            for (int i = 0; i < 8; ++i) p[i][j] *= inv;
        }
    }

#pragma unroll
    for (int i = 0; i < 8; ++i)
#pragma unroll
        for (int j = 0; j < 8; ++j)
            p[i][j] = (p[i][j] > THR) ? p[i][j] : 0.f;

    // A@V with V streamed in two j-halves (register pressure)
    float o8[8][4];
#pragma unroll
    for (int i = 0; i < 8; ++i)
#pragma unroll
        for (int d = 0; d < 4; ++d) o8[i][d] = 0.f;
#pragma unroll
    for (int jh = 0; jh < 8; jh += 4) {
        float vf[4][4];
#pragma unroll
        for (int j = 0; j < 4; ++j)
#pragma unroll
            for (int d = 0; d < 4; ++d)
                vf[j][d] = Vh[8 * cg + jh + j][cb + d];
#pragma unroll
        for (int i = 0; i < 8; ++i)
#pragma unroll
            for (int j = 0; j < 4; ++j) {
                o8[i][0] = fmaf(p[i][jh + j], vf[j][0], o8[i][0]);
                o8[i][1] = fmaf(p[i][jh + j], vf[j][1], o8[i][1]);
                o8[i][2] = fmaf(p[i][jh + j], vf[j][2], o8[i][2]);
                o8[i][3] = fmaf(p[i][jh + j], vf[j][3], o8[i][3]);
            }
    }
#pragma unroll
    for (int i = 0; i < 8; ++i)
#pragma unroll
        for (int d = 0; d < 4; ++d) {
            float v = o8[i][d];
            v += __shfl_xor(v, 1, 64);
            v += __shfl_xor(v, 2, 64);
            v += __shfl_xor(v, 4, 64);
            o8[i][d] = v;
        }

    // static select of row i == cg (no runtime register indexing!)
    float tva0 = o8[0][0], tva1 = o8[0][1], tva2 = o8[0][2], tva3 = o8[0][3];
#pragma unroll
    for (int i = 1; i < 8; ++i) {
        if (cg == i) {
            tva0 = o8[i][0]; tva1 = o8[i][1];
            tva2 = o8[i][2]; tva3 = o8[i][3];
        }
    }

    // fused loss for row n = 8rg+cg, global cols half*32 + cb + d
    float l1 = 0.f, l2 = 0.f, l3 = 0.f;
    {
        const int n = 8 * rg + cg;
#pragma unroll
        for (int d = 0; d < 4; ++d) {
            const int cl = cb + d;
            const int c  = half * 32 + cl;
            float tv;
            if (n < 2) {
                const int idx = n * 64 + c;
                tv = (idx < 100) ? env[b * 100 + idx] : 0.f;
            } else {
                tv = (d == 0) ? tva0 : (d == 1) ? tva1 : (d == 2) ? tva2 : tva3;
            }
            const float pv = Vh[n][cl];
            const float kk = Kh[n][cl];
            const float qv = Qh[n][cl];
            const float sv = Ss[n][c];
            const float d1 = pv - tv;
            const float d2 = kk - sv;
            const float d3 = qv - tv;
            l1 = fmaf(d1, d1, l1);
            l2 = fmaf(d2, d2, l2);
            l3 = fmaf(d3, d3, l3);
        }
    }
#pragma unroll
    for (int o = 1; o <= 32; o <<= 1) {
        l1 += __shfl_xor(l1, o, 64);
        l2 += __shfl_xor(l2, o, 64);
        l3 += __shfl_xor(l3, o, 64);
    }
    if (l == 0) { redL[wave][0] = l1; redL[wave][1] = l2; redL[wave][2] = l3; }
    __syncthreads();
    if (threadIdx.x == 0) {
        float s1 = 0.f, s2 = 0.f, s3 = 0.f;
#pragma unroll
        for (int wv = 0; wv < 8; ++wv) {
            s1 += redL[wv][0]; s2 += redL[wv][1]; s3 += redL[wv][2];
        }
        part[blockIdx.x]        = s1;
        part[512 + blockIdx.x]  = s2;
        part[1024 + blockIdx.x] = s3;
    }
}

// ---------------------------------------------------------------------------
// Final reduce -> scalar loss
// ---------------------------------------------------------------------------
__global__ __launch_bounds__(256) void loss_final_kernel(
    const float* __restrict__ part, float* __restrict__ out)
{
    float a = 0.f;
    for (int i = threadIdx.x; i < 1536; i += 256) a += part[i];
#pragma unroll
    for (int o = 32; o >= 1; o >>= 1) a += __shfl_xor(a, o, 64);
    __shared__ float red[4];
    const int wv = threadIdx.x >> 6, ln = threadIdx.x & 63;
    if (ln == 0) red[wv] = a;
    __syncthreads();
    if (threadIdx.x == 0) {
        out[0] = (red[0] + red[1] + red[2] + red[3]) * (1.0f / (float)TOT);
    }
}

extern "C" void kernel_launch(void* const* d_in, const int* in_sizes, int n_in,
                              void* d_out, int out_size, void* d_ws, size_t ws_size,
                              hipStream_t stream)
{
    const float* env   = (const float*)d_in[0];
    const float* state = (const float*)d_in[1];
    const float* w1    = (const float*)d_in[2];
    const float* w2    = (const float*)d_in[3];
    const float* w3    = (const float*)d_in[4];
    float* out = (float*)d_out;
    float* part = (float*)d_ws;    // 1536 floats

    hipLaunchKernelGGL(fused_brain_kernel, dim3(512), dim3(512), 0, stream,
                       env, state, w1, w2, w3, part);
    hipLaunchKernelGGL(loss_final_kernel, dim3(1), dim3(256), 0, stream,
                       part, out);
}

// Round 9
// 168.061 us; speedup vs baseline: 1.4385x; 1.0732x over previous
//
#include <hip/hip_runtime.h>
#include <math.h>

#define TOT (256*64*64)          // 1048576
#define EPS_SINK 1e-8f
#define THR (1.0f/64.0f)
#define INV_BSCALE 0.5412658773652741f   // 1/sqrt(2+sqrt(2))
#define UNTANH_A 0.6f

typedef float nativef4 __attribute__((ext_vector_type(4)));

static __device__ __forceinline__ float buntanh(float x) {
    return (tanhf(x) + UNTANH_A * x) * INV_BSCALE;
}

#if __has_builtin(__builtin_amdgcn_rcpf)
static __device__ __forceinline__ float fastrcp(float x) {
    return __builtin_amdgcn_rcpf(x);
}
#else
static __device__ __forceinline__ float fastrcp(float x) { return 1.0f / x; }
#endif

// ---------------------------------------------------------------------------
// Fused kernel v2: one block per b. 1024 threads = 16 waves.
// Phase 1 (gemv): r3's proven pattern — lane (k4=l&15, jg=l>>4) reads W rows
//   [16jg,16jg+16) x cols 4k4..+3 as 16 NT dwordx4 (4x256B segments/instr,
//   full row covered by the wave), state fragment from global (L1-hot),
//   reduce over jg = xor16+32, jg==0 lanes write float4 -> LDS [64][65].
//   12 full gemvs per wave (192 = 3 weights x 64 rows), contiguous 192KB
//   stream per wave.
// Phase 2 (attn): 16 waves = 16 heads. Register-resident sinkhorn (proven),
//   zero barriers, static select for the o8 row, fused loss; state re-read
//   from global for the keys-loss.
// ---------------------------------------------------------------------------
__global__ __launch_bounds__(1024, 4) void fused_brain_kernel(
    const float* __restrict__ env, const float* __restrict__ state,
    const float* __restrict__ w1, const float* __restrict__ w2,
    const float* __restrict__ w3, float* __restrict__ part)
{
    __shared__ float Vh[64][65];     // pred
    __shared__ float Kh[64][65];     // keys
    __shared__ float Qh[64][65];     // queries
    __shared__ float redL[16][3];

    const int b    = blockIdx.x;
    const int wave = threadIdx.x >> 6;   // 0..15
    const int l    = threadIdx.x & 63;
    const int k4   = l & 15;
    const int jg   = l >> 4;

    // ---- phase 1: 12 gemvs per wave ----
#pragma unroll 2
    for (int tt = 0; tt < 12; ++tt) {
        const int task = wave * 12 + tt;      // 0..191
        const int widx = task >> 6;           // 0,1,2
        const int n    = task & 63;
        const float* __restrict__ w =
            (widx == 0) ? w1 : (widx == 1) ? w2 : w3;
        const size_t bn = (size_t)(b * 64 + n);

        // state fragment: s[j] for j in [16jg, 16jg+16), from global (L1)
        const float* sp = state + bn * 64 + jg * 16;
        float s[16];
#pragma unroll
        for (int i = 0; i < 4; ++i) {
            const float4 v = *(const float4*)(sp + 4 * i);
            s[4 * i + 0] = v.x; s[4 * i + 1] = v.y;
            s[4 * i + 2] = v.z; s[4 * i + 3] = v.w;
        }

        const nativef4* wp = (const nativef4*)(w + bn * 4096 +
                                               (size_t)(jg * 16) * 64 + k4 * 4);
        float a0 = 0.f, a1 = 0.f, a2 = 0.f, a3 = 0.f;
#pragma unroll
        for (int jj = 0; jj < 16; ++jj) {
            const nativef4 wv = __builtin_nontemporal_load(wp + jj * 16);
            a0 = fmaf(s[jj], wv.x, a0);
            a1 = fmaf(s[jj], wv.y, a1);
            a2 = fmaf(s[jj], wv.z, a2);
            a3 = fmaf(s[jj], wv.w, a3);
        }
        a0 += __shfl_xor(a0, 16, 64); a0 += __shfl_xor(a0, 32, 64);
        a1 += __shfl_xor(a1, 16, 64); a1 += __shfl_xor(a1, 32, 64);
        a2 += __shfl_xor(a2, 16, 64); a2 += __shfl_xor(a2, 32, 64);
        a3 += __shfl_xor(a3, 16, 64); a3 += __shfl_xor(a3, 32, 64);
        if (jg == 0) {
            float* dst = (widx == 0) ? &Vh[n][4 * k4]
                       : (widx == 1) ? &Kh[n][4 * k4] : &Qh[n][4 * k4];
            dst[0] = buntanh(a0);
            dst[1] = buntanh(a1);
            dst[2] = buntanh(a2);
            dst[3] = buntanh(a3);
        }
    }
    __syncthreads();

    // ---- phase 2: attention + sinkhorn + loss. wave = head h ----
    const int cb = 4 * wave;        // column base of this head
    const int rg = l >> 3;          // rows 8rg..+7
    const int cg = l & 7;           // cols 8cg..+7

    float p[8][8];
    float ss = 0.f, mx = -1e30f;
    {
        float kq[8][4];
#pragma unroll
        for (int j = 0; j < 8; ++j)
#pragma unroll
            for (int d = 0; d < 4; ++d)
                kq[j][d] = Kh[8 * cg + j][cb + d];
#pragma unroll
        for (int i = 0; i < 8; ++i) {
            const float q0 = Qh[8 * rg + i][cb + 0];
            const float q1 = Qh[8 * rg + i][cb + 1];
            const float q2 = Qh[8 * rg + i][cb + 2];
            const float q3 = Qh[8 * rg + i][cb + 3];
#pragma unroll
            for (int j = 0; j < 8; ++j) {
                const float e = (q0 * kq[j][0] + q1 * kq[j][1] +
                                 q2 * kq[j][2] + q3 * kq[j][3]) * 0.5f;
                p[i][j] = e;
                ss += e * e;
                mx = fmaxf(mx, e);
            }
        }
    }
#pragma unroll
    for (int o = 1; o <= 32; o <<= 1) {
        ss += __shfl_xor(ss, o, 64);
        mx = fmaxf(mx, __shfl_xor(mx, o, 64));
    }
    const float scale = rsqrtf(ss * (1.0f / 4096.0f) + 1e-6f);  // SHARPNESS=1

#pragma unroll
    for (int i = 0; i < 8; ++i)
#pragma unroll
        for (int j = 0; j < 8; ++j)
            p[i][j] = __expf(scale * (p[i][j] - mx));

    for (int it = 0; it < 10; ++it) {
#pragma unroll
        for (int i = 0; i < 8; ++i) {
            float r = ((p[i][0] + p[i][1]) + (p[i][2] + p[i][3])) +
                      ((p[i][4] + p[i][5]) + (p[i][6] + p[i][7]));
            r += __shfl_xor(r, 1, 64);
            r += __shfl_xor(r, 2, 64);
            r += __shfl_xor(r, 4, 64);
            const float inv = fastrcp(r + EPS_SINK);
#pragma unroll
            for (int j = 0; j < 8; ++j) p[i][j] *= inv;
        }
#pragma unroll
        for (int j = 0; j < 8; ++j) {
            float c = ((p[0][j] + p[1][j]) + (p[2][j] + p[3][j])) +
                      ((p[4][j] + p[5][j]) + (p[6][j] + p[7][j]));
            c += __shfl_xor(c, 8, 64);
            c += __shfl_xor(c, 16, 64);
            c += __shfl_xor(c, 32, 64);
            const float inv = fastrcp(c + EPS_SINK);
#pragma unroll
            for (int i = 0; i < 8; ++i) p[i][j] *= inv;
        }
    }

#pragma unroll
    for (int i = 0; i < 8; ++i)
#pragma unroll
        for (int j = 0; j < 8; ++j)
            p[i][j] = (p[i][j] > THR) ? p[i][j] : 0.f;

    // A@V: V streamed in two j-halves
    float o8[8][4];
#pragma unroll
    for (int i = 0; i < 8; ++i)
#pragma unroll
        for (int d = 0; d < 4; ++d) o8[i][d] = 0.f;
#pragma unroll
    for (int jh = 0; jh < 8; jh += 4) {
        float vf[4][4];
#pragma unroll
        for (int j = 0; j < 4; ++j)
#pragma unroll
            for (int d = 0; d < 4; ++d)
                vf[j][d] = Vh[8 * cg + jh + j][cb + d];
#pragma unroll
        for (int i = 0; i < 8; ++i)
#pragma unroll
            for (int j = 0; j < 4; ++j) {
                o8[i][0] = fmaf(p[i][jh + j], vf[j][0], o8[i][0]);
                o8[i][1] = fmaf(p[i][jh + j], vf[j][1], o8[i][1]);
                o8[i][2] = fmaf(p[i][jh + j], vf[j][2], o8[i][2]);
                o8[i][3] = fmaf(p[i][jh + j], vf[j][3], o8[i][3]);
            }
    }
#pragma unroll
    for (int i = 0; i < 8; ++i)
#pragma unroll
        for (int d = 0; d < 4; ++d) {
            float v = o8[i][d];
            v += __shfl_xor(v, 1, 64);
            v += __shfl_xor(v, 2, 64);
            v += __shfl_xor(v, 4, 64);
            o8[i][d] = v;
        }

    // static select of row i == cg (no runtime register indexing)
    float tva0 = o8[0][0], tva1 = o8[0][1], tva2 = o8[0][2], tva3 = o8[0][3];
#pragma unroll
    for (int i = 1; i < 8; ++i) {
        if (cg == i) {
            tva0 = o8[i][0]; tva1 = o8[i][1];
            tva2 = o8[i][2]; tva3 = o8[i][3];
        }
    }

    // fused loss for row n = 8rg+cg, cols cb..cb+3
    float l1 = 0.f, l2 = 0.f, l3 = 0.f;
    {
        const int n = 8 * rg + cg;
        const float* srow = state + ((size_t)(b * 64 + n)) * 64;
#pragma unroll
        for (int d = 0; d < 4; ++d) {
            const int c = cb + d;
            float tv;
            if (n < 2) {
                const int idx = n * 64 + c;
                tv = (idx < 100) ? env[b * 100 + idx] : 0.f;
            } else {
                tv = (d == 0) ? tva0 : (d == 1) ? tva1 : (d == 2) ? tva2 : tva3;
            }
            const float pv = Vh[n][c];
            const float kk = Kh[n][c];
            const float qv = Qh[n][c];
            const float sv = srow[c];
            const float d1 = pv - tv;
            const float d2 = kk - sv;
            const float d3 = qv - tv;
            l1 = fmaf(d1, d1, l1);
            l2 = fmaf(d2, d2, l2);
            l3 = fmaf(d3, d3, l3);
        }
    }
#pragma unroll
    for (int o = 1; o <= 32; o <<= 1) {
        l1 += __shfl_xor(l1, o, 64);
        l2 += __shfl_xor(l2, o, 64);
        l3 += __shfl_xor(l3, o, 64);
    }
    if (l == 0) { redL[wave][0] = l1; redL[wave][1] = l2; redL[wave][2] = l3; }
    __syncthreads();
    if (threadIdx.x == 0) {
        float s1 = 0.f, s2 = 0.f, s3 = 0.f;
#pragma unroll
        for (int wv = 0; wv < 16; ++wv) {
            s1 += redL[wv][0]; s2 += redL[wv][1]; s3 += redL[wv][2];
        }
        part[b]       = s1;
        part[256 + b] = s2;
        part[512 + b] = s3;
    }
}

// ---------------------------------------------------------------------------
// Final reduce -> scalar loss
// ---------------------------------------------------------------------------
__global__ __launch_bounds__(256) void loss_final_kernel(
    const float* __restrict__ part, float* __restrict__ out)
{
    float a = 0.f;
    for (int i = threadIdx.x; i < 768; i += 256) a += part[i];
#pragma unroll
    for (int o = 32; o >= 1; o >>= 1) a += __shfl_xor(a, o, 64);
    __shared__ float red[4];
    const int wv = threadIdx.x >> 6, ln = threadIdx.x & 63;
    if (ln == 0) red[wv] = a;
    __syncthreads();
    if (threadIdx.x == 0) {
        out[0] = (red[0] + red[1] + red[2] + red[3]) * (1.0f / (float)TOT);
    }
}

extern "C" void kernel_launch(void* const* d_in, const int* in_sizes, int n_in,
                              void* d_out, int out_size, void* d_ws, size_t ws_size,
                              hipStream_t stream)
{
    const float* env   = (const float*)d_in[0];
    const float* state = (const float*)d_in[1];
    const float* w1    = (const float*)d_in[2];
    const float* w2    = (const float*)d_in[3];
    const float* w3    = (const float*)d_in[4];
    float* out = (float*)d_out;
    float* part = (float*)d_ws;    // 768 floats

    hipLaunchKernelGGL(fused_brain_kernel, dim3(256), dim3(1024), 0, stream,
                       env, state, w1, w2, w3, part);
    hipLaunchKernelGGL(loss_final_kernel, dim3(1), dim3(256), 0, stream,
                       part, out);
}